// Round 4
// baseline (12238.523 us; speedup 1.0000x reference)
//
#include <hip/hip_runtime.h>
#include <hip/hip_bf16.h>

namespace {
constexpr int Nn = 50000;
constexpr int Ee = 800000;
constexpr int Pp = 500000;
constexpr int Hh = 128;
constexpr int Ll = 4;

__device__ __forceinline__ float silu_f(float x) {
  return x / (1.0f + __expf(-x));
}
__device__ __forceinline__ float sigmoid_f(float x) {
  return 1.0f / (1.0f + __expf(-x));
}
__device__ __forceinline__ float bf2f(unsigned short u) {
  union { unsigned int i; float f; } x;
  x.i = ((unsigned int)u) << 16;
  return x.f;
}
__device__ __forceinline__ unsigned short f2bf(float f) {
  union { float f; unsigned int i; } x;
  x.f = f;
  unsigned int r = x.i + 0x7fffu + ((x.i >> 16) & 1u);
  return (unsigned short)(r >> 16);
}

// h[n][:] = node_embedding; msum = 0
__global__ __launch_bounds__(256) void init_nodes_kernel(
    float* __restrict__ h, float* __restrict__ msum,
    const float* __restrict__ emb) {
  int idx = blockIdx.x * 256 + threadIdx.x;  // float4 index over N*32
  int c4 = idx & 31;
  float4 ev = *(const float4*)(emb + c4 * 4);
  *(float4*)(h + (size_t)idx * 4) = ev;
  *(float4*)(msum + (size_t)idx * 4) = make_float4(0.f, 0.f, 0.f, 0.f);
}

// e[i][j] = silu(silu(edge_d[i]*We[j] + be[j]))
template <bool EF32>
__global__ __launch_bounds__(256) void edge_init_kernel(
    void* __restrict__ e_, const float* __restrict__ edge_d,
    const float* __restrict__ We, const float* __restrict__ be) {
  int idx = blockIdx.x * 256 + threadIdx.x;  // 4-elem group over E*32
  int r = idx >> 5, c4 = idx & 31;
  float d = edge_d[r];
  float4 w = *(const float4*)(We + c4 * 4);
  float4 b = *(const float4*)(be + c4 * 4);
  float4 v;
  v.x = silu_f(silu_f(d * w.x + b.x));
  v.y = silu_f(silu_f(d * w.y + b.y));
  v.z = silu_f(silu_f(d * w.z + b.z));
  v.w = silu_f(silu_f(d * w.w + b.w));
  if constexpr (EF32) {
    *(float4*)((float*)e_ + (size_t)idx * 4) = v;
  } else {
    ushort4 u;
    u.x = f2bf(v.x); u.y = f2bf(v.y); u.z = f2bf(v.z); u.w = f2bf(v.w);
    *(ushort4*)((unsigned short*)e_ + (size_t)idx * 4) = u;
  }
}

// Fused edge message: Z = silu([h[src],h[dst],e] @ W1 + b1); M = silu(Z @ W2 + b2)
// e += M; gate = sigmoid(M @ sw + sb); atomic msum[dst] += M*gate
template <bool EF32>
__global__ __launch_bounds__(256, 2) void edge_msg_kernel(
    const float* __restrict__ h, void* __restrict__ e_,
    float* __restrict__ msum, const int* __restrict__ src,
    const int* __restrict__ dst, const float* __restrict__ W1,
    const float* __restrict__ b1, const float* __restrict__ W2,
    const float* __restrict__ b2, const float* __restrict__ sw,
    const float* __restrict__ sb) {
  __shared__ float lds[12544];
  __shared__ int s_src[64], s_dst[64];
  float* Xs = lds;          // [64][68]
  float* Ws = lds + 4352;   // [64][128]
  float* Zs = lds;          // [64][132]
  float* W2s = lds + 8448;  // [32][128]

  const int tid = threadIdx.x;
  const int tx = tid & 15;
  const int ty = tid >> 4;
  const int edge0 = blockIdx.x * 64;

  if (tid < 64)
    s_src[tid] = src[edge0 + tid];
  else if (tid < 128)
    s_dst[tid - 64] = dst[edge0 + tid - 64];

  float acc[4][8];
#pragma unroll
  for (int i = 0; i < 4; ++i)
#pragma unroll
    for (int j = 0; j < 8; ++j) acc[i][j] = 0.f;

  // GEMM1: K = 384 in 6 chunks of 64
  for (int c = 0; c < 6; ++c) {
    __syncthreads();
    // stage X chunk: 64 rows x 64 cols
#pragma unroll
    for (int it = 0; it < 4; ++it) {
      int idx = it * 256 + tid;
      int r = idx >> 4, c4 = idx & 15;
      float4 v;
      if (c < 4) {
        const float* rp = (c < 2) ? (h + (size_t)s_src[r] * Hh + c * 64)
                                  : (h + (size_t)s_dst[r] * Hh + (c - 2) * 64);
        v = *(const float4*)(rp + c4 * 4);
      } else {
        if constexpr (EF32) {
          const float* rp = (const float*)e_ + (size_t)(edge0 + r) * Hh + (c - 4) * 64;
          v = *(const float4*)(rp + c4 * 4);
        } else {
          const unsigned short* rp =
              (const unsigned short*)e_ + (size_t)(edge0 + r) * Hh + (c - 4) * 64;
          ushort4 u = *(const ushort4*)(rp + c4 * 4);
          v.x = bf2f(u.x); v.y = bf2f(u.y); v.z = bf2f(u.z); v.w = bf2f(u.w);
        }
      }
      *(float4*)&Xs[r * 68 + c4 * 4] = v;
    }
    // stage W1 chunk: rows c*64..c*64+63 (64x128)
    {
      const float* wp = W1 + (size_t)c * 64 * Hh;
#pragma unroll
      for (int it = 0; it < 8; ++it) {
        int idx = it * 256 + tid;
        *(float4*)&Ws[idx * 4] = *(const float4*)(wp + idx * 4);
      }
    }
    __syncthreads();
#pragma unroll 4
    for (int k = 0; k < 64; ++k) {
      float w[8];
      *(float4*)&w[0] = *(const float4*)&Ws[k * Hh + tx * 8];
      *(float4*)&w[4] = *(const float4*)&Ws[k * Hh + tx * 8 + 4];
      float a[4];
#pragma unroll
      for (int i = 0; i < 4; ++i) a[i] = Xs[(ty * 4 + i) * 68 + k];
#pragma unroll
      for (int i = 0; i < 4; ++i)
#pragma unroll
        for (int j = 0; j < 8; ++j) acc[i][j] = fmaf(a[i], w[j], acc[i][j]);
    }
  }
  // bias + silu
  {
    float bb[8];
    *(float4*)&bb[0] = *(const float4*)(b1 + tx * 8);
    *(float4*)&bb[4] = *(const float4*)(b1 + tx * 8 + 4);
#pragma unroll
    for (int i = 0; i < 4; ++i)
#pragma unroll
      for (int j = 0; j < 8; ++j) acc[i][j] = silu_f(acc[i][j] + bb[j]);
  }
  __syncthreads();  // GEMM1 LDS reads done; safe to overwrite
  // write Z to LDS
#pragma unroll
  for (int i = 0; i < 4; ++i) {
    *(float4*)&Zs[(ty * 4 + i) * 132 + tx * 8] = *(float4*)&acc[i][0];
    *(float4*)&Zs[(ty * 4 + i) * 132 + tx * 8 + 4] = *(float4*)&acc[i][4];
  }
  float acc2[4][8];
#pragma unroll
  for (int i = 0; i < 4; ++i)
#pragma unroll
    for (int j = 0; j < 8; ++j) acc2[i][j] = 0.f;

  // GEMM2: K = 128 in 4 chunks of 32
  for (int c = 0; c < 4; ++c) {
    if (c) __syncthreads();
    const float* wp = W2 + (size_t)c * 32 * Hh;
#pragma unroll
    for (int it = 0; it < 4; ++it) {
      int idx = it * 256 + tid;
      *(float4*)&W2s[idx * 4] = *(const float4*)(wp + idx * 4);
    }
    __syncthreads();
#pragma unroll 4
    for (int k = 0; k < 32; ++k) {
      float w[8];
      *(float4*)&w[0] = *(const float4*)&W2s[k * Hh + tx * 8];
      *(float4*)&w[4] = *(const float4*)&W2s[k * Hh + tx * 8 + 4];
      float a[4];
#pragma unroll
      for (int i = 0; i < 4; ++i) a[i] = Zs[(ty * 4 + i) * 132 + c * 32 + k];
#pragma unroll
      for (int i = 0; i < 4; ++i)
#pragma unroll
        for (int j = 0; j < 8; ++j) acc2[i][j] = fmaf(a[i], w[j], acc2[i][j]);
    }
  }
  // epilogue
  float bb2[8], sww[8];
  *(float4*)&bb2[0] = *(const float4*)(b2 + tx * 8);
  *(float4*)&bb2[4] = *(const float4*)(b2 + tx * 8 + 4);
  *(float4*)&sww[0] = *(const float4*)(sw + tx * 8);
  *(float4*)&sww[4] = *(const float4*)(sw + tx * 8 + 4);
  float sbv = sb[0];
#pragma unroll
  for (int i = 0; i < 4; ++i) {
    float part = 0.f;
#pragma unroll
    for (int j = 0; j < 8; ++j) {
      float mm = silu_f(acc2[i][j] + bb2[j]);
      acc2[i][j] = mm;
      part = fmaf(mm, sww[j], part);
    }
#pragma unroll
    for (int s = 1; s < 16; s <<= 1) part += __shfl_xor(part, s);
    float gate = sigmoid_f(part + sbv);
    int row = ty * 4 + i;
    // e += m (RMW)
    if constexpr (EF32) {
      float* ep = (float*)e_ + (size_t)(edge0 + row) * Hh + tx * 8;
      float4 e0 = *(float4*)ep;
      float4 e1 = *(float4*)(ep + 4);
      e0.x += acc2[i][0]; e0.y += acc2[i][1];
      e0.z += acc2[i][2]; e0.w += acc2[i][3];
      e1.x += acc2[i][4]; e1.y += acc2[i][5];
      e1.z += acc2[i][6]; e1.w += acc2[i][7];
      *(float4*)ep = e0;
      *(float4*)(ep + 4) = e1;
    } else {
      unsigned short* ep =
          (unsigned short*)e_ + (size_t)(edge0 + row) * Hh + tx * 8;
      ushort4 lo = *(ushort4*)ep;
      ushort4 hi = *(ushort4*)(ep + 4);
      lo.x = f2bf(bf2f(lo.x) + acc2[i][0]);
      lo.y = f2bf(bf2f(lo.y) + acc2[i][1]);
      lo.z = f2bf(bf2f(lo.z) + acc2[i][2]);
      lo.w = f2bf(bf2f(lo.w) + acc2[i][3]);
      hi.x = f2bf(bf2f(hi.x) + acc2[i][4]);
      hi.y = f2bf(bf2f(hi.y) + acc2[i][5]);
      hi.z = f2bf(bf2f(hi.z) + acc2[i][6]);
      hi.w = f2bf(bf2f(hi.w) + acc2[i][7]);
      *(ushort4*)ep = lo;
      *(ushort4*)(ep + 4) = hi;
    }
    // msum[dst] += m*gate
    float* mp = msum + (size_t)s_dst[row] * Hh + tx * 8;
#pragma unroll
    for (int j = 0; j < 8; ++j) unsafeAtomicAdd(mp + j, acc2[i][j] * gate);
  }
}

// Fused node update: T = h + msum; Z = silu(T@U1+b1); h += Z@U2 + b2; msum = 0
__global__ __launch_bounds__(256, 2) void node_upd_kernel(
    float* __restrict__ h, float* __restrict__ msum,
    const float* __restrict__ U1, const float* __restrict__ b1,
    const float* __restrict__ U2, const float* __restrict__ b2) {
  __shared__ float lds[12544];
  float* Ts = lds;         // [64][132]
  float* Wc = lds + 8448;  // [32][128]
  const int tid = threadIdx.x;
  const int tx = tid & 15, ty = tid >> 4;
  const int row0 = blockIdx.x * 64;

  // stage T = h + msum, zero msum
#pragma unroll
  for (int it = 0; it < 8; ++it) {
    int idx = it * 256 + tid;  // float4 over 64x32
    int r = idx >> 5, c4 = idx & 31;
    int n = row0 + r;
    float4 t = make_float4(0.f, 0.f, 0.f, 0.f);
    if (n < Nn) {
      float4 hv = *(const float4*)&h[(size_t)n * Hh + c4 * 4];
      float4 mv = *(const float4*)&msum[(size_t)n * Hh + c4 * 4];
      t.x = hv.x + mv.x; t.y = hv.y + mv.y;
      t.z = hv.z + mv.z; t.w = hv.w + mv.w;
      *(float4*)&msum[(size_t)n * Hh + c4 * 4] = make_float4(0.f, 0.f, 0.f, 0.f);
    }
    *(float4*)&Ts[r * 132 + c4 * 4] = t;
  }
  float acc[4][8];
#pragma unroll
  for (int i = 0; i < 4; ++i)
#pragma unroll
    for (int j = 0; j < 8; ++j) acc[i][j] = 0.f;
  // GEMM A: K=128, 4 chunks of 32
  for (int c = 0; c < 4; ++c) {
    if (c) __syncthreads();
    const float* wp = U1 + (size_t)c * 32 * Hh;
#pragma unroll
    for (int it = 0; it < 4; ++it) {
      int idx = it * 256 + tid;
      *(float4*)&Wc[idx * 4] = *(const float4*)(wp + idx * 4);
    }
    __syncthreads();
#pragma unroll 4
    for (int k = 0; k < 32; ++k) {
      float w[8];
      *(float4*)&w[0] = *(const float4*)&Wc[k * Hh + tx * 8];
      *(float4*)&w[4] = *(const float4*)&Wc[k * Hh + tx * 8 + 4];
      float a[4];
#pragma unroll
      for (int i = 0; i < 4; ++i) a[i] = Ts[(ty * 4 + i) * 132 + c * 32 + k];
#pragma unroll
      for (int i = 0; i < 4; ++i)
#pragma unroll
        for (int j = 0; j < 8; ++j) acc[i][j] = fmaf(a[i], w[j], acc[i][j]);
    }
  }
  {
    float bb[8];
    *(float4*)&bb[0] = *(const float4*)(b1 + tx * 8);
    *(float4*)&bb[4] = *(const float4*)(b1 + tx * 8 + 4);
#pragma unroll
    for (int i = 0; i < 4; ++i)
#pragma unroll
      for (int j = 0; j < 8; ++j) acc[i][j] = silu_f(acc[i][j] + bb[j]);
  }
  __syncthreads();
#pragma unroll
  for (int i = 0; i < 4; ++i) {
    *(float4*)&Ts[(ty * 4 + i) * 132 + tx * 8] = *(float4*)&acc[i][0];
    *(float4*)&Ts[(ty * 4 + i) * 132 + tx * 8 + 4] = *(float4*)&acc[i][4];
  }
  float acc2[4][8];
#pragma unroll
  for (int i = 0; i < 4; ++i)
#pragma unroll
    for (int j = 0; j < 8; ++j) acc2[i][j] = 0.f;
  // GEMM B
  for (int c = 0; c < 4; ++c) {
    if (c) __syncthreads();
    const float* wp = U2 + (size_t)c * 32 * Hh;
#pragma unroll
    for (int it = 0; it < 4; ++it) {
      int idx = it * 256 + tid;
      *(float4*)&Wc[idx * 4] = *(const float4*)(wp + idx * 4);
    }
    __syncthreads();
#pragma unroll 4
    for (int k = 0; k < 32; ++k) {
      float w[8];
      *(float4*)&w[0] = *(const float4*)&Wc[k * Hh + tx * 8];
      *(float4*)&w[4] = *(const float4*)&Wc[k * Hh + tx * 8 + 4];
      float a[4];
#pragma unroll
      for (int i = 0; i < 4; ++i) a[i] = Ts[(ty * 4 + i) * 132 + c * 32 + k];
#pragma unroll
      for (int i = 0; i < 4; ++i)
#pragma unroll
        for (int j = 0; j < 8; ++j) acc2[i][j] = fmaf(a[i], w[j], acc2[i][j]);
    }
  }
  // h += acc2 + b2
  float bb2[8];
  *(float4*)&bb2[0] = *(const float4*)(b2 + tx * 8);
  *(float4*)&bb2[4] = *(const float4*)(b2 + tx * 8 + 4);
#pragma unroll
  for (int i = 0; i < 4; ++i) {
    int n = row0 + ty * 4 + i;
    if (n < Nn) {
      float* hp = h + (size_t)n * Hh + tx * 8;
      float4 h0 = *(float4*)hp;
      float4 h1 = *(float4*)(hp + 4);
      h0.x += acc2[i][0] + bb2[0]; h0.y += acc2[i][1] + bb2[1];
      h0.z += acc2[i][2] + bb2[2]; h0.w += acc2[i][3] + bb2[3];
      h1.x += acc2[i][4] + bb2[4]; h1.y += acc2[i][5] + bb2[5];
      h1.z += acc2[i][6] + bb2[6]; h1.w += acc2[i][7] + bb2[7];
      *(float4*)hp = h0;
      *(float4*)(hp + 4) = h1;
    }
  }
}

// out[p] = softplus( (h[a]+h[b]) . (Wd[:128]+Wd[128:]) + 2*bd )
__global__ __launch_bounds__(256) void pair_kernel(
    float* __restrict__ out, const float* __restrict__ h,
    const int* __restrict__ pidx, const float* __restrict__ Wd,
    const float* __restrict__ bd) {
  const int tid = threadIdx.x;
  const int lane = tid & 15;
  const int p = blockIdx.x * 16 + (tid >> 4);
  int a = pidx[p];
  int b = pidx[Pp + p];
  const float* ha = h + (size_t)a * Hh + lane * 8;
  const float* hb = h + (size_t)b * Hh + lane * 8;
  float w0[8], w1[8];
  *(float4*)&w0[0] = *(const float4*)(Wd + lane * 8);
  *(float4*)&w0[4] = *(const float4*)(Wd + lane * 8 + 4);
  *(float4*)&w1[0] = *(const float4*)(Wd + 128 + lane * 8);
  *(float4*)&w1[4] = *(const float4*)(Wd + 128 + lane * 8 + 4);
  float4 a0 = *(const float4*)ha, a1 = *(const float4*)(ha + 4);
  float4 b0 = *(const float4*)hb, b1 = *(const float4*)(hb + 4);
  float s[8] = {a0.x + b0.x, a0.y + b0.y, a0.z + b0.z, a0.w + b0.w,
                a1.x + b1.x, a1.y + b1.y, a1.z + b1.z, a1.w + b1.w};
  float dot = 0.f;
#pragma unroll
  for (int j = 0; j < 8; ++j) dot = fmaf(s[j], w0[j] + w1[j], dot);
#pragma unroll
  for (int t = 1; t < 16; t <<= 1) dot += __shfl_xor(dot, t);
  if (lane == 0) {
    float x = dot + 2.f * bd[0];
    out[p] = (x > 20.f) ? x : log1pf(expf(x));
  }
}

}  // namespace

extern "C" void kernel_launch(void* const* d_in, const int* in_sizes, int n_in,
                              void* d_out, int out_size, void* d_ws,
                              size_t ws_size, hipStream_t stream) {
  const float* edge_d = (const float*)d_in[0];
  const float* node_emb = (const float*)d_in[1];
  const float* We = (const float*)d_in[2];
  const float* be = (const float*)d_in[3];
  const float* msg_W1 = (const float*)d_in[4];
  const float* msg_b1 = (const float*)d_in[5];
  const float* msg_W2 = (const float*)d_in[6];
  const float* msg_b2 = (const float*)d_in[7];
  const float* soft_w = (const float*)d_in[8];
  const float* soft_b = (const float*)d_in[9];
  const float* upd_W1 = (const float*)d_in[10];
  const float* upd_b1 = (const float*)d_in[11];
  const float* upd_W2 = (const float*)d_in[12];
  const float* upd_b2 = (const float*)d_in[13];
  const float* Wd = (const float*)d_in[14];
  const float* bd = (const float*)d_in[15];
  const int* src = (const int*)d_in[16];
  const int* dst = (const int*)d_in[17];
  const int* pidx = (const int*)d_in[18];
  // d_in[19] (mask) and d_in[20] (graph_ids) are unused by the output.
  float* out = (float*)d_out;

  // Workspace layout: h, msum first (fixed 51.2 MB), then e (f32 if it
  // fits in ws_size, else bf16). ws_size is constant across calls, so this
  // host-side branch is deterministic (graph-capture safe).
  float* h = (float*)d_ws;                 // [N][128]  25.6 MB
  float* msum = h + (size_t)Nn * Hh;       // [N][128]  25.6 MB
  void* e = (void*)(msum + (size_t)Nn * Hh);
  const size_t base = (size_t)2 * Nn * Hh * sizeof(float);
  const size_t e_f32_bytes = (size_t)Ee * Hh * sizeof(float);
  const bool ef32 = ws_size >= base + e_f32_bytes;

  init_nodes_kernel<<<(Nn * 32) / 256, 256, 0, stream>>>(h, msum, node_emb);
  if (ef32) {
    edge_init_kernel<true><<<(Ee * 32) / 256, 256, 0, stream>>>(e, edge_d, We, be);
    for (int l = 0; l < Ll; ++l) {
      edge_msg_kernel<true><<<Ee / 64, 256, 0, stream>>>(
          h, e, msum, src, dst, msg_W1 + (size_t)l * 3 * Hh * Hh,
          msg_b1 + l * Hh, msg_W2 + (size_t)l * Hh * Hh, msg_b2 + l * Hh,
          soft_w + l * Hh, soft_b + l);
      node_upd_kernel<<<(Nn + 63) / 64, 256, 0, stream>>>(
          h, msum, upd_W1 + (size_t)l * Hh * Hh, upd_b1 + l * Hh,
          upd_W2 + (size_t)l * Hh * Hh, upd_b2 + l * Hh);
    }
  } else {
    edge_init_kernel<false><<<(Ee * 32) / 256, 256, 0, stream>>>(e, edge_d, We, be);
    for (int l = 0; l < Ll; ++l) {
      edge_msg_kernel<false><<<Ee / 64, 256, 0, stream>>>(
          h, e, msum, src, dst, msg_W1 + (size_t)l * 3 * Hh * Hh,
          msg_b1 + l * Hh, msg_W2 + (size_t)l * Hh * Hh, msg_b2 + l * Hh,
          soft_w + l * Hh, soft_b + l);
      node_upd_kernel<<<(Nn + 63) / 64, 256, 0, stream>>>(
          h, msum, upd_W1 + (size_t)l * Hh * Hh, upd_b1 + l * Hh,
          upd_W2 + (size_t)l * Hh * Hh, upd_b2 + l * Hh);
    }
  }
  pair_kernel<<<Pp / 16, 256, 0, stream>>>(out, h, pidx, Wd, bd);
}